// Round 10
// baseline (1975.802 us; speedup 1.0000x reference)
//
#include <hip/hip_runtime.h>

#define L_SEQ 512
#define BATCH 32
#define EMB 256
#define HID 256
#define G3 768
#define H2V 512
#define NFEAT 512
#define LOG2E 1.44269504f

typedef __bf16 bf16x8 __attribute__((ext_vector_type(8)));
typedef float f32x4 __attribute__((ext_vector_type(4)));
typedef unsigned short u16;
typedef unsigned int u32;

__device__ __forceinline__ u16 f2bf(float f) {
  u32 u = __builtin_bit_cast(u32, f);
  u32 r = (u + 0x7fffu + ((u >> 16) & 1u)) >> 16;
  return (u16)r;
}
__device__ __forceinline__ float bf2f(u16 b) {
  return __builtin_bit_cast(float, ((u32)b) << 16);
}
__device__ __forceinline__ float lo_bf(u32 u) {
  return __builtin_bit_cast(float, u << 16);
}
__device__ __forceinline__ float hi_bf(u32 u) {
  return __builtin_bit_cast(float, u & 0xFFFF0000u);
}

// Merged prep: all fp32->bf16 weight conversions in ONE launch.
// task (blockIdx.y): 0 wih0, 1 whh0(scaled), 2 wih1, 3 whh1(scaled),
//                    4 law, 5 faw, 6 v, 7 fe
__global__ void k_prep(const float* __restrict__ wih0, const float* __restrict__ whh0,
                       const float* __restrict__ wih1, const float* __restrict__ whh1,
                       const float* __restrict__ law,  const float* __restrict__ faw,
                       const float* __restrict__ vmat, const float* __restrict__ fe,
                       u16* wih0b, u16* whh0b, u16* wih1b, u16* whh1b,
                       u16* lawb, u16* fawb, u16* vb, u16* feb) {
  const float* s; u16* d; int n; int whh = 0;
  switch (blockIdx.y) {
    case 0: s = wih0; d = wih0b; n = 393216; break;
    case 1: s = whh0; d = whh0b; n = 393216; whh = 1; break;
    case 2: s = wih1; d = wih1b; n = 786432; break;
    case 3: s = whh1; d = whh1b; n = 393216; whh = 1; break;
    case 4: s = law;  d = lawb;  n = 131072; break;
    case 5: s = faw;  d = fawb;  n = 131072; break;
    case 6: s = vmat; d = vb;    n = 32768;  break;
    default: s = fe;  d = feb;   n = 98304;  break;
  }
  int i = blockIdx.x * blockDim.x + threadIdx.x;
  int st = gridDim.x * blockDim.x;
  for (; i < n; i += st) {
    float sc = 1.0f;
    if (whh) {
      int row = i >> 8;                    // / HID
      if (row >= 768) row -= 768;
      sc = (row >= 512) ? (2.0f * LOG2E) : LOG2E;
    }
    d[i] = f2bf(s[i] * sc);
  }
}

// both layers' combined bias in one launch. blockIdx.x = layer*2 + dir
__global__ void k_mkbias2(const float* __restrict__ bih0, const float* __restrict__ bhh0,
                          const float* __restrict__ bih1, const float* __restrict__ bhh1,
                          float* __restrict__ cb0, float* __restrict__ cb1) {
  int idx = blockIdx.x, d = idx & 1, t = threadIdx.x;
  const float* bih = (idx >> 1) ? bih1 : bih0;
  const float* bhh = (idx >> 1) ? bhh1 : bhh0;
  float* cb = (idx >> 1) ? cb1 : cb0;
  float v = bih[d * G3 + t];
  if (t < 512) v += bhh[d * G3 + t];     // bhh_r, bhh_z additive pre-sigmoid; bhh_n NOT foldable
  cb[d * G3 + t] = v;
}

// bcomb[f] = dot(fe[f,:], fa_b) for f<384 ; dot(v[f-384,:], la_b) otherwise (fp32)
__global__ __launch_bounds__(512) void k_dotb(const float* __restrict__ fe,
    const float* __restrict__ fab, const float* __restrict__ vmat,
    const float* __restrict__ lab, float* __restrict__ bcomb) {
  int f = threadIdx.x;
  const float* row; const float* bvec;
  if (f < 384) { row = fe + (size_t)f * 256;  bvec = fab; }
  else         { row = vmat + (size_t)(f - 384) * 256; bvec = lab; }
  float s = 0.f;
  #pragma unroll 8
  for (int i = 0; i < 256; i++) s = __builtin_fmaf(row[i], bvec[i], s);
  bcomb[f] = s;
}

__global__ __launch_bounds__(256) void k_embed(const int* __restrict__ ids,
    const float* __restrict__ emb, u16* __restrict__ x) {
  int blk = blockIdx.x;            // l*32 + b
  int l = blk >> 5, b = blk & 31;
  int row = ids[b * L_SEQ + l];
  x[(size_t)blk * EMB + threadIdx.x] = f2bf(emb[(size_t)row * EMB + threadIdx.x]);
}

// NT GEMM: C(M,N) = A(M,K)bf16 * B(N,K)bf16 (+bias). TRANS_B: B is (K,N) row-major.
// C_MODE: 0 = fp32, 1 = bf16, 2 = bf16 packed+scaled (log2e; n-gate 2*log2e) for k_gru.
template<int TRANS_B, int C_MODE, int ADD_BIAS>
__global__ __launch_bounds__(256) void k_gemm(
    const u16* __restrict__ A, const u16* __restrict__ B, void* __restrict__ Cv,
    const float* __restrict__ bias, int K, int lda, int ldb, int ldc,
    long sA, long sB, long sC, long sBias)
{
  __shared__ __align__(16) u16 As[64][40];
  __shared__ __align__(16) u16 Bs[64][40];
  const int z = blockIdx.z;
  A += z * sA; B += z * sB;
  const int m0 = blockIdx.y * 64, n0 = blockIdx.x * 64;
  const int t = threadIdx.x;
  const int wave = t >> 6, lane = t & 63, lhi = lane >> 4, llo = lane & 15;
  f32x4 acc[4] = {};
  const int ar = t >> 2, ak = (t & 3) * 8;
  const int bkr = t >> 3, bnn = (t & 7) * 8;
  for (int k0 = 0; k0 < K; k0 += 32) {
    uint4 av = *(const uint4*)(A + (long)(m0 + ar) * lda + k0 + ak);
    *(uint4*)&As[ar][ak] = av;
    if (!TRANS_B) {
      uint4 bv = *(const uint4*)(B + (long)(n0 + ar) * ldb + k0 + ak);
      *(uint4*)&Bs[ar][ak] = bv;
    } else {
      uint4 bv = *(const uint4*)(B + (long)(k0 + bkr) * ldb + n0 + bnn);
      u16 tmp[8];
      *(uint4*)tmp = bv;
      #pragma unroll
      for (int i = 0; i < 8; i++) Bs[bnn + i][bkr] = tmp[i];
    }
    __syncthreads();
    bf16x8 a = __builtin_bit_cast(bf16x8, *(const uint4*)&As[16 * wave + llo][lhi * 8]);
    #pragma unroll
    for (int j = 0; j < 4; j++) {
      bf16x8 b = __builtin_bit_cast(bf16x8, *(const uint4*)&Bs[16 * j + llo][lhi * 8]);
      acc[j] = __builtin_amdgcn_mfma_f32_16x16x32_bf16(a, b, acc[j], 0, 0, 0);
    }
    __syncthreads();
  }
  #pragma unroll
  for (int j = 0; j < 4; j++) {
    float bv = 0.f;
    if (ADD_BIAS) bv = bias[z * sBias + n0 + 16 * j + llo];
    #pragma unroll
    for (int r = 0; r < 4; r++) {
      long row = m0 + 16 * wave + lhi * 4 + r;
      long col = n0 + 16 * j + llo;
      float vv = acc[j][r] + bv;
      if (C_MODE == 2) {
        // pack for k_gru: dir z, l = row>>5, b = row&31, g = col>>8, cc = col&255
        int b = (int)(row & 31);
        long l = row >> 5;
        int cc = (int)(col & 255), g = (int)(col >> 8);
        vv *= (g == 2) ? (2.0f * LOG2E) : LOG2E;
        long idx = ((l * 2 + (b >> 4)) * 512 + (cc >> 5) * 64 + ((b & 15) >> 2) * 16 + (cc & 15)) * 24
                   + g * 8 + ((cc >> 4) & 1) * 4 + (b & 3);
        ((u16*)Cv)[z * sC + idx] = f2bf(vv);
      } else if (C_MODE == 1) {
        ((u16*)Cv)[z * sC + row * ldc + col] = f2bf(vv);
      } else {
        ((float*)Cv)[z * sC + row * ldc + col] = vv;
      }
    }
  }
}

// GRU recurrence, flag-synced, DATA-rotated weights (static register indexing).
// grid = 4: dir*2 + batch_half. 512 threads (8 waves). Wave w owns gh cols
// [32w,32w+32) for all 3 gates -> produces h-chunk w. MFMA visits h-chunks
// (w+j)&7 with PRELOAD-rotated weight k-slices (static register indexing).
// R3-verified core (788us). R9: s_sleep(1) in the spin (free issue slots for
// working waves; flags always advance -> no deadlock) + s_setprio(1) around
// the compute regions (waves are phase-split: spinners vs compute -> the
// scheduler-arbitration case where setprio pays). n weights stream from LDS
// (128KB/step = structural floor; register-resident proven infeasible).
__global__ __launch_bounds__(512, 2) void k_gru(
    const u16* __restrict__ whh, const float* __restrict__ bhh,
    const u16* __restrict__ gi, const float* __restrict__ h0,
    u16* __restrict__ out)
{
  const int dir = blockIdx.x >> 1;
  const int half = blockIdx.x & 1;
  const int b0 = half * 16;
  extern __shared__ __align__(16) char smem[];
  uint4 (*ldsB)[2][8][64] = (uint4(*)[2][8][64])smem;                 // 128 KB
  u16 (*h_lds)[16][264] = (u16(*)[16][264])(smem + 131072);           // 16896 B
  int* hflag = (int*)(smem + 131072 + 16896);                          // 8 ints
  const int t = threadIdx.x;
  const int w = t >> 6, lane = t & 63, lhi = lane >> 4, llo = lane & 15;
  const u16* whh_d = whh + dir * G3 * HID;

  // r,z tiles -> registers, k-chunks ROTATED: breg[tt][j] = k-chunk (w+j)&7
  uint4 breg[4][8];
  #pragma unroll
  for (int tt = 0; tt < 4; tt++) {
    const int g = tt >> 1, jj = tt & 1;
    const u16* bp = whh_d + (size_t)(g * 256 + 32 * w + 16 * jj + llo) * HID + lhi * 8;
    #pragma unroll
    for (int j = 0; j < 8; j++) {
      const int kc = (w + j) & 7;
      breg[tt][j] = *(const uint4*)(bp + kc * 32);
    }
  }
  // n tiles -> LDS, same rotation: ldsB[w][jj][j][lane] = k-chunk (w+j)&7
  #pragma unroll
  for (int jj = 0; jj < 2; jj++) {
    const u16* bp = whh_d + (size_t)(512 + 32 * w + 16 * jj + llo) * HID + lhi * 8;
    #pragma unroll
    for (int j = 0; j < 8; j++) {
      const int kc = (w + j) & 7;
      ldsB[w][jj][j][lane] = *(const uint4*)(bp + kc * 32);
    }
  }
  // h0 -> h_lds[0] (A layout)
  {
    int m = t >> 5, c0 = (t & 31) * 8;
    const float* hp = h0 + (size_t)(dir * BATCH + b0 + m) * HID + c0;
    float4 f0 = *(const float4*)(hp);
    float4 f1 = *(const float4*)(hp + 4);
    u16 hh[8] = {f2bf(f0.x), f2bf(f0.y), f2bf(f0.z), f2bf(f0.w),
                 f2bf(f1.x), f2bf(f1.y), f2bf(f1.z), f2bf(f1.w)};
    *(uint4*)&h_lds[0][m][c0] = *(uint4*)hh;
  }
  // h_old in C-layout registers
  float hreg[8];
  #pragma unroll
  for (int jj = 0; jj < 2; jj++)
    #pragma unroll
    for (int r = 0; r < 4; r++)
      hreg[jj * 4 + r] = h0[(size_t)(dir * BATCH + b0 + lhi * 4 + r) * HID + 32 * w + 16 * jj + llo];
  const float bn0 = bhh[dir * G3 + 512 + 32 * w + llo] * (2.0f * LOG2E);
  const float bn1 = bhh[dir * G3 + 512 + 32 * w + 16 + llo] * (2.0f * LOG2E);

  if (t < 8) hflag[t] = 0;    // hflag[c] = v  <=>  h(v) chunk c readable

  const int l0 = dir ? (L_SEQ - 1) : 0;
  const u16* gp = gi + (size_t)dir * 12582912 + (((size_t)l0 * 2 + half) * 512 + t) * 24;
  const long gdelta = dir ? -24576 : 24576;
  u16* ob = out + ((size_t)l0 * BATCH + b0 + lhi * 4) * H2V + dir * HID + 32 * w + llo;
  const long odelta = dir ? -(long)BATCH * H2V : (long)BATCH * H2V;
  __syncthreads();

  for (int s = 0; s < L_SEQ; s++) {
    const int rd = s & 1, wr = rd ^ 1;
    uint4 q0 = *(const uint4*)(gp);
    uint4 q1 = *(const uint4*)(gp + 8);
    uint4 q2 = *(const uint4*)(gp + 16);
    gp += gdelta;

    f32x4 acc[6];
    #pragma unroll
    for (int tt = 0; tt < 4; tt++) acc[tt] = (f32x4){0.f, 0.f, 0.f, 0.f};
    acc[4] = (f32x4){bn0, bn0, bn0, bn0};
    acc[5] = (f32x4){bn1, bn1, bn1, bn1};

    // j=0: own chunk, no wait (written by this wave last step; DS in-order)
    __builtin_amdgcn_s_setprio(1);
    {
      bf16x8 a = __builtin_bit_cast(bf16x8, *(const uint4*)&h_lds[rd][llo][w * 32 + lhi * 8]);
      uint4 b4 = ldsB[w][0][0][lane];
      uint4 b5 = ldsB[w][1][0][lane];
      #pragma unroll
      for (int tt = 0; tt < 4; tt++)
        acc[tt] = __builtin_amdgcn_mfma_f32_16x16x32_bf16(
            a, __builtin_bit_cast(bf16x8, breg[tt][0]), acc[tt], 0, 0, 0);
      acc[4] = __builtin_amdgcn_mfma_f32_16x16x32_bf16(
          a, __builtin_bit_cast(bf16x8, b4), acc[4], 0, 0, 0);
      acc[5] = __builtin_amdgcn_mfma_f32_16x16x32_bf16(
          a, __builtin_bit_cast(bf16x8, b5), acc[5], 0, 0, 0);
    }
    __builtin_amdgcn_s_setprio(0);
    // ONE combined wait: all 8 chunks of h(s) published. Sleep between polls
    // so spinners don't steal VALU/LDS issue slots from working waves.
    for (;;) {
      int fv = __hip_atomic_load(&hflag[lane & 7], __ATOMIC_ACQUIRE, __HIP_MEMORY_SCOPE_WORKGROUP);
      if (__all(fv >= s)) break;
      __builtin_amdgcn_s_sleep(1);
    }
    __builtin_amdgcn_s_setprio(1);
    // chunks 1..7: reads batch-issue, compiler interleaves lgkmcnt with MFMAs
    #pragma unroll
    for (int j = 1; j < 8; j++) {
      const int c = (w + j) & 7;
      bf16x8 a = __builtin_bit_cast(bf16x8, *(const uint4*)&h_lds[rd][llo][c * 32 + lhi * 8]);
      uint4 b4 = ldsB[w][0][j][lane];
      uint4 b5 = ldsB[w][1][j][lane];
      #pragma unroll
      for (int tt = 0; tt < 4; tt++)
        acc[tt] = __builtin_amdgcn_mfma_f32_16x16x32_bf16(
            a, __builtin_bit_cast(bf16x8, breg[tt][j]), acc[tt], 0, 0, 0);
      acc[4] = __builtin_amdgcn_mfma_f32_16x16x32_bf16(
          a, __builtin_bit_cast(bf16x8, b4), acc[4], 0, 0, 0);
      acc[5] = __builtin_amdgcn_mfma_f32_16x16x32_bf16(
          a, __builtin_bit_cast(bf16x8, b5), acc[5], 0, 0, 0);
    }

    u32 qw[12];
    *(uint4*)&qw[0] = q0; *(uint4*)&qw[4] = q1; *(uint4*)&qw[8] = q2;
    u16 hb[8];
    #pragma unroll
    for (int jj = 0; jj < 2; jj++) {
      #pragma unroll
      for (int rp = 0; rp < 2; rp++) {
        const u32 ur = qw[jj * 2 + rp], uz = qw[4 + jj * 2 + rp], un = qw[8 + jj * 2 + rp];
        #pragma unroll
        for (int e = 0; e < 2; e++) {
          const int r_ = rp * 2 + e, o = jj * 4 + r_;
          const float gr = e ? hi_bf(ur) : lo_bf(ur);
          const float gz = e ? hi_bf(uz) : lo_bf(uz);
          const float gn = e ? hi_bf(un) : lo_bf(un);
          float rr = __builtin_amdgcn_rcpf(1.f + __builtin_amdgcn_exp2f(-(gr + acc[jj][r_])));
          float zz = __builtin_amdgcn_rcpf(1.f + __builtin_amdgcn_exp2f(-(gz + acc[2 + jj][r_])));
          float q = __builtin_amdgcn_rcpf(1.f + __builtin_amdgcn_exp2f(-(gn + rr * acc[4 + jj][r_])));
          float u = __builtin_fmaf(2.f, q, -1.f);            // tanh
          float hv = __builtin_fmaf(zz, hreg[o] - u, u);
          hreg[o] = hv;
          hb[o] = (u16)((__builtin_bit_cast(u32, hv) + 0x8000u) >> 16);
        }
      }
    }
    // h chunk w -> LDS, then release-publish (still high prio), then stores
    #pragma unroll
    for (int jj = 0; jj < 2; jj++)
      #pragma unroll
      for (int r_ = 0; r_ < 4; r_++)
        h_lds[wr][lhi * 4 + r_][32 * w + 16 * jj + llo] = hb[jj * 4 + r_];
    if (lane == 0)
      __hip_atomic_store(&hflag[w], s + 1, __ATOMIC_RELEASE, __HIP_MEMORY_SCOPE_WORKGROUP);
    __builtin_amdgcn_s_setprio(0);
    #pragma unroll
    for (int jj = 0; jj < 2; jj++)
      #pragma unroll
      for (int r_ = 0; r_ < 4; r_++)
        ob[r_ * H2V + jj * 16] = hb[jj * 4 + r_];
    ob += odelta;
  }
}

// Fused softmax + transpose: energy (L,B,F) fp32 -> aout (B,F,L) fp32 and
// Pb (B,F,L) bf16, softmax over F. One block per (l-tile 64, b). Row cache
// tile[64][513] (513 stride: bank (row+col)%32 -> conflict-free column reads).
__global__ __launch_bounds__(256) void k_smt(const float* __restrict__ E,
    float* __restrict__ aout, u16* __restrict__ Pb)
{
  const int l0 = blockIdx.x * 64, b = blockIdx.y;
  extern __shared__ float fsm[];
  float (*tile)[513] = (float(*)[513])fsm;              // 64*513
  float* pmax4 = fsm + 64 * 513;                         // [4][64]
  float* psum4 = pmax4 + 256;                            // [4][64]
  float* inv   = psum4 + 256;                            // [64]
  const int t = threadIdx.x, w = t >> 6, lane = t & 63;
  // load 64 rows x 512 cols (rows are energy rows (l0+li)*B + b)
  for (int k = 0; k < 128; k++) {
    int idx = k * 256 + t;
    int li = idx >> 9, col = idx & 511;
    tile[li][col] = E[((long)(l0 + li) * BATCH + b) * NFEAT + col];
  }
  __syncthreads();
  // pass 1: max. wave w scans cols [128w,128w+128) of row = lane
  float m = -3.4e38f;
  for (int i = 0; i < 128; i++) m = fmaxf(m, tile[lane][128 * w + i]);
  pmax4[w * 64 + lane] = m;
  __syncthreads();
  float mx = fmaxf(fmaxf(pmax4[lane], pmax4[64 + lane]),
                   fmaxf(pmax4[128 + lane], pmax4[192 + lane]));
  // pass 2: exp + partial sum (overwrite tile with exp values)
  float s = 0.f;
  for (int i = 0; i < 128; i++) {
    float e = __expf(tile[lane][128 * w + i] - mx);
    tile[lane][128 * w + i] = e;
    s += e;
  }
  psum4[w * 64 + lane] = s;
  __syncthreads();
  if (w == 0)
    inv[lane] = 1.0f / (psum4[lane] + psum4[64 + lane] + psum4[128 + lane] + psum4[192 + lane]);
  __syncthreads();
  // transpose write: wave w handles f = 4k + w; lane = l index (coalesced)
  for (int k = 0; k < 128; k++) {
    int f = k * 4 + w;
    float val = tile[lane][f] * inv[lane];
    long idx = ((long)b * NFEAT + f) * L_SEQ + l0 + lane;
    aout[idx] = val;
    Pb[idx] = f2bf(val);
  }
}

extern "C" void kernel_launch(void* const* d_in, const int* in_sizes, int n_in,
                              void* d_out, int out_size, void* d_ws, size_t ws_size,
                              hipStream_t stream)
{
  const int* ids      = (const int*)d_in[0];
  const float* hidden = (const float*)d_in[2];
  const float* fe     = (const float*)d_in[3];
  const float* emb    = (const float*)d_in[4];
  const float* wih0   = (const float*)d_in[5];
  const float* whh0   = (const float*)d_in[6];
  const float* bih0   = (const float*)d_in[7];
  const float* bhh0   = (const float*)d_in[8];
  const float* wih1   = (const float*)d_in[9];
  const float* whh1   = (const float*)d_in[10];
  const float* bih1   = (const float*)d_in[11];
  const float* bhh1   = (const float*)d_in[12];
  const float* law    = (const float*)d_in[13];
  const float* lab    = (const float*)d_in[14];
  const float* faw    = (const float*)d_in[15];
  const float* fab    = (const float*)d_in[16];
  const float* vmat   = (const float*)d_in[17];

  char* w = (char*)d_ws;
  size_t o = 0;
  auto alloc = [&](size_t elems, size_t esz) {
    void* p = w + o; o = (o + elems * esz + 255) & ~(size_t)255; return p;
  };
  u16* wih0b = (u16*)alloc((size_t)2 * 768 * 256, 2);
  u16* whh0b = (u16*)alloc((size_t)2 * 768 * 256, 2);
  u16* wih1b = (u16*)alloc((size_t)2 * 768 * 512, 2);
  u16* whh1b = (u16*)alloc((size_t)2 * 768 * 256, 2);
  u16* lawb  = (u16*)alloc((size_t)256 * 512, 2);
  u16* fawb  = (u16*)alloc((size_t)256 * 512, 2);
  u16* vb    = (u16*)alloc((size_t)128 * 256, 2);
  u16* feb   = (u16*)alloc((size_t)384 * 256, 2);
  u16* xb    = (u16*)alloc((size_t)16384 * 256, 2);
  u16* gi0   = (u16*)alloc((size_t)2 * 16384 * 768, 2);
  u16* out0  = (u16*)alloc((size_t)16384 * 512, 2);
  u16* gi1   = (u16*)alloc((size_t)2 * 16384 * 768, 2);
  u16* rnn   = (u16*)alloc((size_t)16384 * 512, 2);
  u16* wcomb = (u16*)alloc((size_t)512 * 512, 2);
  float* bcomb = (float*)alloc((size_t)512, 4);
  float* energy = (float*)alloc((size_t)16384 * 512, 4);
  u16* Pb    = (u16*)alloc((size_t)16384 * 512, 2);
  float* cbias0 = (float*)alloc((size_t)2 * 768, 4);
  float* cbias1 = (float*)alloc((size_t)2 * 768, 4);

  // all weight conversions (1 launch) + combined biases (1 launch)
  k_prep<<<dim3(192, 8), 256, 0, stream>>>(wih0, whh0, wih1, whh1, law, faw, vmat, fe,
      wih0b, whh0b, wih1b, whh1b, lawb, fawb, vb, feb);
  k_mkbias2<<<4, 768, 0, stream>>>(bih0, bhh0, bih1, bhh1, cbias0, cbias1);
  k_embed<<<16384, 256, 0, stream>>>(ids, emb, xb);

  // Wcomb = concat(fe@fa_w, v@la_w)  (512,512) bf16 ; bcomb = concat(fe.fab, v.lab)
  k_gemm<1, 1, 0><<<dim3(8, 6, 1), 256, 0, stream>>>(feb, fawb, wcomb, nullptr,
      256, 256, 512, 512, 0L, 0L, 0L, 0L);
  k_gemm<1, 1, 0><<<dim3(8, 2, 1), 256, 0, stream>>>(vb, lawb, wcomb + 384 * 512, nullptr,
      256, 256, 512, 512, 0L, 0L, 0L, 0L);
  k_dotb<<<1, 512, 0, stream>>>(fe, fab, vmat, lab, bcomb);

  // gi0 = (x @ wih0^T + (bih0 + bhh0[r,z])) * scale, packed for k_gru
  k_gemm<0, 2, 1><<<dim3(12, 256, 2), 256, 0, stream>>>(xb, wih0b, gi0, cbias0,
      256, 256, 256, 768, 0L, 768L * 256, 12582912L, 768L);
  k_gru<<<4, 512, 148000, stream>>>(whh0b, bhh0, gi0, hidden, out0);

  // gi1 = (out0 @ wih1^T + (bih1 + bhh1[r,z])) * scale, packed
  k_gemm<0, 2, 1><<<dim3(12, 256, 2), 256, 0, stream>>>(out0, wih1b, gi1, cbias1,
      512, 512, 512, 768, 0L, 768L * 512, 12582912L, 768L);
  k_gru<<<4, 512, 148000, stream>>>(whh1b, bhh1, gi1, hidden + 2 * 32 * 256, rnn);

  // energy = rnn @ Wcomb^T + bcomb   (fp32, (L*B, 512))
  k_gemm<0, 0, 1><<<dim3(8, 256, 1), 256, 0, stream>>>(rnn, wcomb, energy, bcomb,
      512, 512, 512, 512, 0L, 0L, 0L, 0L);

  float* attn_out = (float*)d_out + (size_t)32 * 512 * 512;
  // fused softmax + transpose (energy left unnormalized; only aout/Pb used)
  k_smt<<<dim3(8, 32), 256, 133632, stream>>>(energy, attn_out, Pb);

  // context[b] = P[b](F,L) @ rnn(:,b,:)(L,2H)  -> d_out (B,F,2H) fp32
  k_gemm<1, 0, 0><<<dim3(8, 8, 32), 256, 0, stream>>>(Pb, rnn, (float*)d_out, nullptr,
      512, 512, 16384, 512, (long)512 * 512, 512L, (long)512 * 512, 0L);
}

// Round 11
// 1933.649 us; speedup vs baseline: 1.0218x; 1.0218x over previous
//
#include <hip/hip_runtime.h>

#define L_SEQ 512
#define BATCH 32
#define EMB 256
#define HID 256
#define G3 768
#define H2V 512
#define NFEAT 512
#define LOG2E 1.44269504f

typedef __bf16 bf16x8 __attribute__((ext_vector_type(8)));
typedef float f32x4 __attribute__((ext_vector_type(4)));
typedef unsigned short u16;
typedef unsigned int u32;

__device__ __forceinline__ u16 f2bf(float f) {
  u32 u = __builtin_bit_cast(u32, f);
  u32 r = (u + 0x7fffu + ((u >> 16) & 1u)) >> 16;
  return (u16)r;
}
__device__ __forceinline__ float bf2f(u16 b) {
  return __builtin_bit_cast(float, ((u32)b) << 16);
}
__device__ __forceinline__ float lo_bf(u32 u) {
  return __builtin_bit_cast(float, u << 16);
}
__device__ __forceinline__ float hi_bf(u32 u) {
  return __builtin_bit_cast(float, u & 0xFFFF0000u);
}

// Merged prep: all fp32->bf16 weight conversions in ONE launch.
// task (blockIdx.y): 0 wih0, 1 whh0(scaled), 2 wih1, 3 whh1(scaled),
//                    4 law, 5 faw, 6 v, 7 fe
__global__ void k_prep(const float* __restrict__ wih0, const float* __restrict__ whh0,
                       const float* __restrict__ wih1, const float* __restrict__ whh1,
                       const float* __restrict__ law,  const float* __restrict__ faw,
                       const float* __restrict__ vmat, const float* __restrict__ fe,
                       u16* wih0b, u16* whh0b, u16* wih1b, u16* whh1b,
                       u16* lawb, u16* fawb, u16* vb, u16* feb) {
  const float* s; u16* d; int n; int whh = 0;
  switch (blockIdx.y) {
    case 0: s = wih0; d = wih0b; n = 393216; break;
    case 1: s = whh0; d = whh0b; n = 393216; whh = 1; break;
    case 2: s = wih1; d = wih1b; n = 786432; break;
    case 3: s = whh1; d = whh1b; n = 393216; whh = 1; break;
    case 4: s = law;  d = lawb;  n = 131072; break;
    case 5: s = faw;  d = fawb;  n = 131072; break;
    case 6: s = vmat; d = vb;    n = 32768;  break;
    default: s = fe;  d = feb;   n = 98304;  break;
  }
  int i = blockIdx.x * blockDim.x + threadIdx.x;
  int st = gridDim.x * blockDim.x;
  for (; i < n; i += st) {
    float sc = 1.0f;
    if (whh) {
      int row = i >> 8;                    // / HID
      if (row >= 768) row -= 768;
      sc = (row >= 512) ? (2.0f * LOG2E) : LOG2E;
    }
    d[i] = f2bf(s[i] * sc);
  }
}

// Merged small-work kernel: blocks 0..3 = combined bias (layer*2+dir);
// block 4 = bcomb[f] = dot(fe[f,:], fa_b) / dot(v[f-384,:], la_b).
__global__ __launch_bounds__(768) void k_small(
    const float* __restrict__ bih0, const float* __restrict__ bhh0,
    const float* __restrict__ bih1, const float* __restrict__ bhh1,
    float* __restrict__ cb0, float* __restrict__ cb1,
    const float* __restrict__ fe, const float* __restrict__ fab,
    const float* __restrict__ vmat, const float* __restrict__ lab,
    float* __restrict__ bcomb) {
  int t = threadIdx.x;
  if (blockIdx.x < 4) {
    int idx = blockIdx.x, d = idx & 1;
    const float* bih = (idx >> 1) ? bih1 : bih0;
    const float* bhh = (idx >> 1) ? bhh1 : bhh0;
    float* cb = (idx >> 1) ? cb1 : cb0;
    float v = bih[d * G3 + t];
    if (t < 512) v += bhh[d * G3 + t];   // bhh_r, bhh_z pre-sigmoid; bhh_n NOT foldable
    cb[d * G3 + t] = v;
  } else if (t < 512) {
    const float* row; const float* bvec;
    if (t < 384) { row = fe + (size_t)t * 256;  bvec = fab; }
    else         { row = vmat + (size_t)(t - 384) * 256; bvec = lab; }
    float s = 0.f;
    #pragma unroll 8
    for (int i = 0; i < 256; i++) s = __builtin_fmaf(row[i], bvec[i], s);
    bcomb[t] = s;
  }
}

// 8 (l,b) rows per block; thread covers 8 cols -> float4 x2 read, uint4 write.
__global__ __launch_bounds__(256) void k_embed(const int* __restrict__ ids,
    const float* __restrict__ emb, u16* __restrict__ x) {
  int rowid = blockIdx.x * 8 + (threadIdx.x >> 5);   // l*32 + b
  int l = rowid >> 5, b = rowid & 31;
  int c0 = (threadIdx.x & 31) * 8;
  long row = ids[b * L_SEQ + l];
  const float* ep = emb + row * 256 + c0;
  float4 f0 = *(const float4*)ep;
  float4 f1 = *(const float4*)(ep + 4);
  u16 hh[8] = {f2bf(f0.x), f2bf(f0.y), f2bf(f0.z), f2bf(f0.w),
               f2bf(f1.x), f2bf(f1.y), f2bf(f1.z), f2bf(f1.w)};
  *(uint4*)&x[(size_t)rowid * 256 + c0] = *(uint4*)hh;
}

// NT GEMM: C(M,N) = A(M,K)bf16 * B(N,K)bf16 (+bias). TRANS_B: B is (K,N) row-major.
// C_MODE: 0 = fp32, 1 = bf16, 2 = bf16 packed+scaled (log2e; n-gate 2*log2e) for k_gru.
template<int TRANS_B, int C_MODE, int ADD_BIAS>
__global__ __launch_bounds__(256) void k_gemm(
    const u16* __restrict__ A, const u16* __restrict__ B, void* __restrict__ Cv,
    const float* __restrict__ bias, int K, int lda, int ldb, int ldc,
    long sA, long sB, long sC, long sBias)
{
  __shared__ __align__(16) u16 As[64][40];
  __shared__ __align__(16) u16 Bs[64][40];
  const int z = blockIdx.z;
  A += z * sA; B += z * sB;
  const int m0 = blockIdx.y * 64, n0 = blockIdx.x * 64;
  const int t = threadIdx.x;
  const int wave = t >> 6, lane = t & 63, lhi = lane >> 4, llo = lane & 15;
  f32x4 acc[4] = {};
  const int ar = t >> 2, ak = (t & 3) * 8;
  const int bkr = t >> 3, bnn = (t & 7) * 8;
  for (int k0 = 0; k0 < K; k0 += 32) {
    uint4 av = *(const uint4*)(A + (long)(m0 + ar) * lda + k0 + ak);
    *(uint4*)&As[ar][ak] = av;
    if (!TRANS_B) {
      uint4 bv = *(const uint4*)(B + (long)(n0 + ar) * ldb + k0 + ak);
      *(uint4*)&Bs[ar][ak] = bv;
    } else {
      uint4 bv = *(const uint4*)(B + (long)(k0 + bkr) * ldb + n0 + bnn);
      u16 tmp[8];
      *(uint4*)tmp = bv;
      #pragma unroll
      for (int i = 0; i < 8; i++) Bs[bnn + i][bkr] = tmp[i];
    }
    __syncthreads();
    bf16x8 a = __builtin_bit_cast(bf16x8, *(const uint4*)&As[16 * wave + llo][lhi * 8]);
    #pragma unroll
    for (int j = 0; j < 4; j++) {
      bf16x8 b = __builtin_bit_cast(bf16x8, *(const uint4*)&Bs[16 * j + llo][lhi * 8]);
      acc[j] = __builtin_amdgcn_mfma_f32_16x16x32_bf16(a, b, acc[j], 0, 0, 0);
    }
    __syncthreads();
  }
  #pragma unroll
  for (int j = 0; j < 4; j++) {
    float bv = 0.f;
    if (ADD_BIAS) bv = bias[z * sBias + n0 + 16 * j + llo];
    #pragma unroll
    for (int r = 0; r < 4; r++) {
      long row = m0 + 16 * wave + lhi * 4 + r;
      long col = n0 + 16 * j + llo;
      float vv = acc[j][r] + bv;
      if (C_MODE == 2) {
        // pack for k_gru: dir z, l = row>>5, b = row&31, g = col>>8, cc = col&255
        int b = (int)(row & 31);
        long l = row >> 5;
        int cc = (int)(col & 255), g = (int)(col >> 8);
        vv *= (g == 2) ? (2.0f * LOG2E) : LOG2E;
        long idx = ((l * 2 + (b >> 4)) * 512 + (cc >> 5) * 64 + ((b & 15) >> 2) * 16 + (cc & 15)) * 24
                   + g * 8 + ((cc >> 4) & 1) * 4 + (b & 3);
        ((u16*)Cv)[z * sC + idx] = f2bf(vv);
      } else if (C_MODE == 1) {
        ((u16*)Cv)[z * sC + row * ldc + col] = f2bf(vv);
      } else {
        ((float*)Cv)[z * sC + row * ldc + col] = vv;
      }
    }
  }
}

// GRU recurrence, flag-synced, DATA-rotated weights (static register indexing).
// grid = 4: dir*2 + batch_half. 512 threads (8 waves). Wave w owns gh cols
// [32w,32w+32) for all 3 gates -> produces h-chunk w. MFMA visits h-chunks
// (w+j)&7 with PRELOAD-rotated weight k-slices. R3-verified core (784us,
// twice-measured). R9's s_sleep/setprio REGRESSED (+18us: wake latency on
// the recurrence critical path) -> reverted. Structure is at its LDS floor:
// per CU-step 64 A-reads + 128 n-weight reads + 64 h-writes ~ 2700cyc on the
// LDS pipe + ~1000 non-hidden VALU = 3690 measured. Register-resident
// n-weights infeasible (budget 256/wave incl AGPR; need 328+, proven
// R1/R2/R6/R7).
__global__ __launch_bounds__(512, 2) void k_gru(
    const u16* __restrict__ whh, const float* __restrict__ bhh,
    const u16* __restrict__ gi, const float* __restrict__ h0,
    u16* __restrict__ out)
{
  const int dir = blockIdx.x >> 1;
  const int half = blockIdx.x & 1;
  const int b0 = half * 16;
  extern __shared__ __align__(16) char smem[];
  uint4 (*ldsB)[2][8][64] = (uint4(*)[2][8][64])smem;                 // 128 KB
  u16 (*h_lds)[16][264] = (u16(*)[16][264])(smem + 131072);           // 16896 B
  int* hflag = (int*)(smem + 131072 + 16896);                          // 8 ints
  const int t = threadIdx.x;
  const int w = t >> 6, lane = t & 63, lhi = lane >> 4, llo = lane & 15;
  const u16* whh_d = whh + dir * G3 * HID;

  // r,z tiles -> registers, k-chunks ROTATED: breg[tt][j] = k-chunk (w+j)&7
  uint4 breg[4][8];
  #pragma unroll
  for (int tt = 0; tt < 4; tt++) {
    const int g = tt >> 1, jj = tt & 1;
    const u16* bp = whh_d + (size_t)(g * 256 + 32 * w + 16 * jj + llo) * HID + lhi * 8;
    #pragma unroll
    for (int j = 0; j < 8; j++) {
      const int kc = (w + j) & 7;
      breg[tt][j] = *(const uint4*)(bp + kc * 32);
    }
  }
  // n tiles -> LDS, same rotation: ldsB[w][jj][j][lane] = k-chunk (w+j)&7
  #pragma unroll
  for (int jj = 0; jj < 2; jj++) {
    const u16* bp = whh_d + (size_t)(512 + 32 * w + 16 * jj + llo) * HID + lhi * 8;
    #pragma unroll
    for (int j = 0; j < 8; j++) {
      const int kc = (w + j) & 7;
      ldsB[w][jj][j][lane] = *(const uint4*)(bp + kc * 32);
    }
  }
  // h0 -> h_lds[0] (A layout)
  {
    int m = t >> 5, c0 = (t & 31) * 8;
    const float* hp = h0 + (size_t)(dir * BATCH + b0 + m) * HID + c0;
    float4 f0 = *(const float4*)(hp);
    float4 f1 = *(const float4*)(hp + 4);
    u16 hh[8] = {f2bf(f0.x), f2bf(f0.y), f2bf(f0.z), f2bf(f0.w),
                 f2bf(f1.x), f2bf(f1.y), f2bf(f1.z), f2bf(f1.w)};
    *(uint4*)&h_lds[0][m][c0] = *(uint4*)hh;
  }
  // h_old in C-layout registers
  float hreg[8];
  #pragma unroll
  for (int jj = 0; jj < 2; jj++)
    #pragma unroll
    for (int r = 0; r < 4; r++)
      hreg[jj * 4 + r] = h0[(size_t)(dir * BATCH + b0 + lhi * 4 + r) * HID + 32 * w + 16 * jj + llo];
  const float bn0 = bhh[dir * G3 + 512 + 32 * w + llo] * (2.0f * LOG2E);
  const float bn1 = bhh[dir * G3 + 512 + 32 * w + 16 + llo] * (2.0f * LOG2E);

  if (t < 8) hflag[t] = 0;    // hflag[c] = v  <=>  h(v) chunk c readable

  const int l0 = dir ? (L_SEQ - 1) : 0;
  const u16* gp = gi + (size_t)dir * 12582912 + (((size_t)l0 * 2 + half) * 512 + t) * 24;
  const long gdelta = dir ? -24576 : 24576;
  u16* ob = out + ((size_t)l0 * BATCH + b0 + lhi * 4) * H2V + dir * HID + 32 * w + llo;
  const long odelta = dir ? -(long)BATCH * H2V : (long)BATCH * H2V;
  __syncthreads();

  for (int s = 0; s < L_SEQ; s++) {
    const int rd = s & 1, wr = rd ^ 1;
    uint4 q0 = *(const uint4*)(gp);
    uint4 q1 = *(const uint4*)(gp + 8);
    uint4 q2 = *(const uint4*)(gp + 16);
    gp += gdelta;

    f32x4 acc[6];
    #pragma unroll
    for (int tt = 0; tt < 4; tt++) acc[tt] = (f32x4){0.f, 0.f, 0.f, 0.f};
    acc[4] = (f32x4){bn0, bn0, bn0, bn0};
    acc[5] = (f32x4){bn1, bn1, bn1, bn1};

    // j=0: own chunk, no wait (written by this wave last step; DS in-order)
    {
      bf16x8 a = __builtin_bit_cast(bf16x8, *(const uint4*)&h_lds[rd][llo][w * 32 + lhi * 8]);
      uint4 b4 = ldsB[w][0][0][lane];
      uint4 b5 = ldsB[w][1][0][lane];
      #pragma unroll
      for (int tt = 0; tt < 4; tt++)
        acc[tt] = __builtin_amdgcn_mfma_f32_16x16x32_bf16(
            a, __builtin_bit_cast(bf16x8, breg[tt][0]), acc[tt], 0, 0, 0);
      acc[4] = __builtin_amdgcn_mfma_f32_16x16x32_bf16(
          a, __builtin_bit_cast(bf16x8, b4), acc[4], 0, 0, 0);
      acc[5] = __builtin_amdgcn_mfma_f32_16x16x32_bf16(
          a, __builtin_bit_cast(bf16x8, b5), acc[5], 0, 0, 0);
    }
    // ONE combined wait: all 8 chunks of h(s) published
    for (;;) {
      int fv = __hip_atomic_load(&hflag[lane & 7], __ATOMIC_ACQUIRE, __HIP_MEMORY_SCOPE_WORKGROUP);
      if (__all(fv >= s)) break;
    }
    // chunks 1..7: reads batch-issue, compiler interleaves lgkmcnt with MFMAs
    #pragma unroll
    for (int j = 1; j < 8; j++) {
      const int c = (w + j) & 7;
      bf16x8 a = __builtin_bit_cast(bf16x8, *(const uint4*)&h_lds[rd][llo][c * 32 + lhi * 8]);
      uint4 b4 = ldsB[w][0][j][lane];
      uint4 b5 = ldsB[w][1][j][lane];
      #pragma unroll
      for (int tt = 0; tt < 4; tt++)
        acc[tt] = __builtin_amdgcn_mfma_f32_16x16x32_bf16(
            a, __builtin_bit_cast(bf16x8, breg[tt][j]), acc[tt], 0, 0, 0);
      acc[4] = __builtin_amdgcn_mfma_f32_16x16x32_bf16(
          a, __builtin_bit_cast(bf16x8, b4), acc[4], 0, 0, 0);
      acc[5] = __builtin_amdgcn_mfma_f32_16x16x32_bf16(
          a, __builtin_bit_cast(bf16x8, b5), acc[5], 0, 0, 0);
    }

    u32 qw[12];
    *(uint4*)&qw[0] = q0; *(uint4*)&qw[4] = q1; *(uint4*)&qw[8] = q2;
    u16 hb[8];
    #pragma unroll
    for (int jj = 0; jj < 2; jj++) {
      #pragma unroll
      for (int rp = 0; rp < 2; rp++) {
        const u32 ur = qw[jj * 2 + rp], uz = qw[4 + jj * 2 + rp], un = qw[8 + jj * 2 + rp];
        #pragma unroll
        for (int e = 0; e < 2; e++) {
          const int r_ = rp * 2 + e, o = jj * 4 + r_;
          const float gr = e ? hi_bf(ur) : lo_bf(ur);
          const float gz = e ? hi_bf(uz) : lo_bf(uz);
          const float gn = e ? hi_bf(un) : lo_bf(un);
          float rr = __builtin_amdgcn_rcpf(1.f + __builtin_amdgcn_exp2f(-(gr + acc[jj][r_])));
          float zz = __builtin_amdgcn_rcpf(1.f + __builtin_amdgcn_exp2f(-(gz + acc[2 + jj][r_])));
          float q = __builtin_amdgcn_rcpf(1.f + __builtin_amdgcn_exp2f(-(gn + rr * acc[4 + jj][r_])));
          float u = __builtin_fmaf(2.f, q, -1.f);            // tanh
          float hv = __builtin_fmaf(zz, hreg[o] - u, u);
          hreg[o] = hv;
          hb[o] = (u16)((__builtin_bit_cast(u32, hv) + 0x8000u) >> 16);
        }
      }
    }
    // h chunk w -> LDS, then release-publish, then global stores (off critical path)
    #pragma unroll
    for (int jj = 0; jj < 2; jj++)
      #pragma unroll
      for (int r_ = 0; r_ < 4; r_++)
        h_lds[wr][lhi * 4 + r_][32 * w + 16 * jj + llo] = hb[jj * 4 + r_];
    if (lane == 0)
      __hip_atomic_store(&hflag[w], s + 1, __ATOMIC_RELEASE, __HIP_MEMORY_SCOPE_WORKGROUP);
    #pragma unroll
    for (int jj = 0; jj < 2; jj++)
      #pragma unroll
      for (int r_ = 0; r_ < 4; r_++)
        ob[r_ * H2V + jj * 16] = hb[jj * 4 + r_];
    ob += odelta;
  }
}

// Fused softmax + transpose: energy (L,B,F) fp32 -> aout (B,F,L) fp32 and
// Pb (B,F,L) bf16, softmax over F. One block per (l-tile 64, b). Row cache
// tile[64][513] (513 stride -> conflict-free column reads).
__global__ __launch_bounds__(256) void k_smt(const float* __restrict__ E,
    float* __restrict__ aout, u16* __restrict__ Pb)
{
  const int l0 = blockIdx.x * 64, b = blockIdx.y;
  extern __shared__ float fsm[];
  float (*tile)[513] = (float(*)[513])fsm;              // 64*513
  float* pmax4 = fsm + 64 * 513;                         // [4][64]
  float* psum4 = pmax4 + 256;                            // [4][64]
  float* inv   = psum4 + 256;                            // [64]
  const int t = threadIdx.x, w = t >> 6, lane = t & 63;
  // load 64 rows x 512 cols (rows are energy rows (l0+li)*B + b)
  for (int k = 0; k < 128; k++) {
    int idx = k * 256 + t;
    int li = idx >> 9, col = idx & 511;
    tile[li][col] = E[((long)(l0 + li) * BATCH + b) * NFEAT + col];
  }
  __syncthreads();
  // pass 1: max. wave w scans cols [128w,128w+128) of row = lane
  float m = -3.4e38f;
  for (int i = 0; i < 128; i++) m = fmaxf(m, tile[lane][128 * w + i]);
  pmax4[w * 64 + lane] = m;
  __syncthreads();
  float mx = fmaxf(fmaxf(pmax4[lane], pmax4[64 + lane]),
                   fmaxf(pmax4[128 + lane], pmax4[192 + lane]));
  // pass 2: exp + partial sum (overwrite tile with exp values)
  float s = 0.f;
  for (int i = 0; i < 128; i++) {
    float e = __expf(tile[lane][128 * w + i] - mx);
    tile[lane][128 * w + i] = e;
    s += e;
  }
  psum4[w * 64 + lane] = s;
  __syncthreads();
  if (w == 0)
    inv[lane] = 1.0f / (psum4[lane] + psum4[64 + lane] + psum4[128 + lane] + psum4[192 + lane]);
  __syncthreads();
  // transpose write: wave w handles f = 4k + w; lane = l index (coalesced)
  for (int k = 0; k < 128; k++) {
    int f = k * 4 + w;
    float val = tile[lane][f] * inv[lane];
    long idx = ((long)b * NFEAT + f) * L_SEQ + l0 + lane;
    aout[idx] = val;
    Pb[idx] = f2bf(val);
  }
}

extern "C" void kernel_launch(void* const* d_in, const int* in_sizes, int n_in,
                              void* d_out, int out_size, void* d_ws, size_t ws_size,
                              hipStream_t stream)
{
  const int* ids      = (const int*)d_in[0];
  const float* hidden = (const float*)d_in[2];
  const float* fe     = (const float*)d_in[3];
  const float* emb    = (const float*)d_in[4];
  const float* wih0   = (const float*)d_in[5];
  const float* whh0   = (const float*)d_in[6];
  const float* bih0   = (const float*)d_in[7];
  const float* bhh0   = (const float*)d_in[8];
  const float* wih1   = (const float*)d_in[9];
  const float* whh1   = (const float*)d_in[10];
  const float* bih1   = (const float*)d_in[11];
  const float* bhh1   = (const float*)d_in[12];
  const float* law    = (const float*)d_in[13];
  const float* lab    = (const float*)d_in[14];
  const float* faw    = (const float*)d_in[15];
  const float* fab    = (const float*)d_in[16];
  const float* vmat   = (const float*)d_in[17];

  char* w = (char*)d_ws;
  size_t o = 0;
  auto alloc = [&](size_t elems, size_t esz) {
    void* p = w + o; o = (o + elems * esz + 255) & ~(size_t)255; return p;
  };
  u16* wih0b = (u16*)alloc((size_t)2 * 768 * 256, 2);
  u16* whh0b = (u16*)alloc((size_t)2 * 768 * 256, 2);
  u16* wih1b = (u16*)alloc((size_t)2 * 768 * 512, 2);
  u16* whh1b = (u16*)alloc((size_t)2 * 768 * 256, 2);
  u16* lawb  = (u16*)alloc((size_t)256 * 512, 2);
  u16* fawb  = (u16*)alloc((size_t)256 * 512, 2);
  u16* vb    = (u16*)alloc((size_t)128 * 256, 2);
  u16* feb   = (u16*)alloc((size_t)384 * 256, 2);
  u16* xb    = (u16*)alloc((size_t)16384 * 256, 2);
  u16* gi0   = (u16*)alloc((size_t)2 * 16384 * 768, 2);
  u16* out0  = (u16*)alloc((size_t)16384 * 512, 2);
  u16* gi1   = (u16*)alloc((size_t)2 * 16384 * 768, 2);
  u16* rnn   = (u16*)alloc((size_t)16384 * 512, 2);
  u16* wcomb = (u16*)alloc((size_t)512 * 512, 2);
  float* bcomb = (float*)alloc((size_t)512, 4);
  float* energy = (float*)alloc((size_t)16384 * 512, 4);
  u16* Pb    = (u16*)alloc((size_t)16384 * 512, 2);
  float* cbias0 = (float*)alloc((size_t)2 * 768, 4);
  float* cbias1 = (float*)alloc((size_t)2 * 768, 4);

  // all weight conversions (1 launch) + bias/bcomb small-work (1 launch)
  k_prep<<<dim3(192, 8), 256, 0, stream>>>(wih0, whh0, wih1, whh1, law, faw, vmat, fe,
      wih0b, whh0b, wih1b, whh1b, lawb, fawb, vb, feb);
  k_small<<<5, 768, 0, stream>>>(bih0, bhh0, bih1, bhh1, cbias0, cbias1,
      fe, fab, vmat, lab, bcomb);
  k_embed<<<2048, 256, 0, stream>>>(ids, emb, xb);

  // Wcomb = concat(fe@fa_w, v@la_w)  (512,512) bf16
  k_gemm<1, 1, 0><<<dim3(8, 6, 1), 256, 0, stream>>>(feb, fawb, wcomb, nullptr,
      256, 256, 512, 512, 0L, 0L, 0L, 0L);
  k_gemm<1, 1, 0><<<dim3(8, 2, 1), 256, 0, stream>>>(vb, lawb, wcomb + 384 * 512, nullptr,
      256, 256, 512, 512, 0L, 0L, 0L, 0L);

  // gi0 = (x @ wih0^T + (bih0 + bhh0[r,z])) * scale, packed for k_gru
  k_gemm<0, 2, 1><<<dim3(12, 256, 2), 256, 0, stream>>>(xb, wih0b, gi0, cbias0,
      256, 256, 256, 768, 0L, 768L * 256, 12582912L, 768L);
  k_gru<<<4, 512, 148000, stream>>>(whh0b, bhh0, gi0, hidden, out0);

  // gi1 = (out0 @ wih1^T + (bih1 + bhh1[r,z])) * scale, packed
  k_gemm<0, 2, 1><<<dim3(12, 256, 2), 256, 0, stream>>>(out0, wih1b, gi1, cbias1,
      512, 512, 512, 768, 0L, 768L * 512, 12582912L, 768L);
  k_gru<<<4, 512, 148000, stream>>>(whh1b, bhh1, gi1, hidden + 2 * 32 * 256, rnn);

  // energy = rnn @ Wcomb^T + bcomb   (fp32, (L*B, 512))
  k_gemm<0, 0, 1><<<dim3(8, 256, 1), 256, 0, stream>>>(rnn, wcomb, energy, bcomb,
      512, 512, 512, 512, 0L, 0L, 0L, 0L);

  float* attn_out = (float*)d_out + (size_t)32 * 512 * 512;
  // fused softmax + transpose (energy left unnormalized; only aout/Pb used)
  k_smt<<<dim3(8, 32), 256, 133632, stream>>>(energy, attn_out, Pb);

  // context[b] = P[b](F,L) @ rnn(:,b,:)(L,2H)  -> d_out (B,F,2H) fp32
  k_gemm<1, 0, 0><<<dim3(8, 8, 32), 256, 0, stream>>>(Pb, rnn, (float*)d_out, nullptr,
      512, 512, 16384, 512, (long)512 * 512, 512L, (long)512 * 512, 0L);
}